// Round 7
// baseline (368.429 us; speedup 1.0000x reference)
//
#include <hip/hip_runtime.h>

#define FEATS 64
#define HSZ   4096
#define ISZ   12480          // (FEATS+1)*FEATS*3
#define I4    (ISZ/4)        // 3120 float4
#define H4    (HSZ/4)        // 1024 float4

// workspace layout (float offsets)
#define X_OFF    0           // 12480
#define GI_OFF   12480       // 12288 (bias folded in)
#define GH_OFF   24768       // 12288 (bias folded in)
#define SYNC_OFF 37056       // int: blocks-done counter

#define GI_RPW 4                      // rows per wave (GI)
#define GI_RPB 16                     // rows per block
#define GH_RPW 12                     // rows per wave (GH), 3 passes of 4
#define GH_RPB 48
#define GI_NB  (3 * HSZ / GI_RPB)     // 768
#define GH_NB  (3 * HSZ / GH_RPB)     // 256  -> 1024 blocks = 4/CU, one pass
#define NBLK   (GI_NB + GH_NB)

typedef float f4 __attribute__((ext_vector_type(4)));

// ---------------- A: GAT, 8 blocks = {feat,time} x 4 head-quarters ------------------
// Softmax is per-head (column), so splitting by heads has no cross-block deps.
__global__ __launch_bounds__(256)
void gat8(const float* __restrict__ data,
          const float* __restrict__ fW, const float* __restrict__ fal,
          const float* __restrict__ fb,
          const float* __restrict__ tW, const float* __restrict__ tal,
          const float* __restrict__ tb,
          float* __restrict__ ws) {
    __shared__ float ld[64][65];   // data (w=0) or data^T (w=1)
    __shared__ float Wl[64][17];   // 16-head slice of W
    __shared__ float hb[64][17];   // h slice
    __shared__ float out0[16];
    int b = blockIdx.x;
    int w = b >> 2, q = b & 3;     // w: which GAT; q: head quarter
    int tid = threadIdx.x;
    const float* Wg = w ? tW  : fW;
    const float* al = w ? tal : fal;
    const float* bb = w ? tb  : fb;

    for (int i = tid; i < 4096; i += 256) {
        int r = i >> 6, c = i & 63;
        float v = data[i];
        if (w) ld[c][r] = v; else ld[r][c] = v;
    }
    for (int i = tid; i < 1024; i += 256) {
        int k = i >> 4, jj = i & 15;
        Wl[k][jj] = Wg[k * 64 + q * 16 + jj];
    }
    __syncthreads();

    // h[v][jj] = sum_k ld[v][k] * Wl[k][jj]; wave jr owns heads jr*4..jr*4+3
    {
        int v = tid & 63, jr = tid >> 6;
        float a0 = 0.f, a1 = 0.f, a2 = 0.f, a3 = 0.f;
        #pragma unroll 8
        for (int k = 0; k < 64; ++k) {
            float dv = ld[v][k];
            a0 = fmaf(dv, Wl[k][jr * 4 + 0], a0);
            a1 = fmaf(dv, Wl[k][jr * 4 + 1], a1);
            a2 = fmaf(dv, Wl[k][jr * 4 + 2], a2);
            a3 = fmaf(dv, Wl[k][jr * 4 + 3], a3);
        }
        hb[v][jr * 4 + 0] = a0;
        hb[v][jr * 4 + 1] = a1;
        hb[v][jr * 4 + 2] = a2;
        hb[v][jr * 4 + 3] = a3;
    }
    __syncthreads();

    // star softmax per head; node 0 has h=0 -> e=0 (ar drops out entirely)
    if (tid < 16) {
        int jj = tid;
        float a = al[q * 16 + jj];
        float m = 0.f;                     // includes node-0 term e=0
        for (int v = 0; v < 64; ++v) {
            float e = hb[v][jj] * a;
            e = e > 0.f ? e : 0.2f * e;
            m = fmaxf(m, e);
        }
        float sum = __expf(0.f - m);       // node-0 term (zero numerator)
        float num = 0.f;
        for (int v = 0; v < 64; ++v) {
            float hv = hb[v][jj];
            float e  = hv * a;
            e = e > 0.f ? e : 0.2f * e;
            float p  = __expf(e - m);
            sum += p;
            num += p * hv;
        }
        out0[jj] = num / sum;
    }
    __syncthreads();

    // x[(n*64+f)*3 + c] for this block's 16 heads: c = 1+w; block w=0 also c0
    for (int i = tid; i < 1040; i += 256) {     // 65 nodes x 16 heads
        int n = i >> 4, ff = i & 15;
        int f = q * 16 + ff;
        float val = ((n == 0) ? out0[ff] : hb[n - 1][ff]) + bb[f];
        ws[X_OFF + (n * 64 + f) * 3 + 1 + w] = val;
        if (w == 0)
            ws[X_OFF + (n * 64 + f) * 3] = (n == 0) ? 0.f : ld[n - 1][f];
    }
}

// ---------------- B: big matvecs (815 MB NT-streamed) + fused GRU combine ----------
__device__ __forceinline__ float wave_reduce(float v) {
    #pragma unroll
    for (int off = 32; off > 0; off >>= 1) v += __shfl_down(v, off);
    return v;
}

__device__ __forceinline__ float fma4(f4 w, f4 v, float a) {
    return fmaf(w.x, v.x, fmaf(w.y, v.y, fmaf(w.z, v.z, fmaf(w.w, v.w, a))));
}

__device__ __forceinline__ f4 ntload(const f4* p) {
    return __builtin_nontemporal_load(p);   // use-once weights: bypass L2 insert
}

__global__ __launch_bounds__(256, 4)
void big_matvec(const float* __restrict__ W_ih,
                const float* __restrict__ W_hh,
                const float* __restrict__ h0,
                const float* __restrict__ b_ih,
                const float* __restrict__ b_hh,
                float* __restrict__ ws,
                float* __restrict__ out) {
    __shared__ int sLast;
    int b    = blockIdx.x;
    int tid  = threadIdx.x;
    int wave = tid >> 6;
    int lane = tid & 63;

    if (b < GI_NB) {
        // 4 rows per wave, 49.9 KB each; x re-read once per 4 rows (L2-resident)
        int r = b * GI_RPB + wave * GI_RPW;
        const f4* x4 = (const f4*)(ws + X_OFF);
        const f4* W0 = (const f4*)W_ih + (size_t)r * I4;
        const f4* W1 = W0 + I4;
        const f4* W2 = W1 + I4;
        const f4* W3 = W2 + I4;
        float a0 = 0.f, a1 = 0.f, a2 = 0.f, a3 = 0.f;
        int k = lane;
        #pragma unroll 4
        for (int i = 0; i < 48; ++i, k += 64) {
            f4 v = x4[k];
            a0 = fma4(ntload(W0 + k), v, a0);
            a1 = fma4(ntload(W1 + k), v, a1);
            a2 = fma4(ntload(W2 + k), v, a2);
            a3 = fma4(ntload(W3 + k), v, a3);
        }
        if (lane < 48) {                       // remainder: 3120 = 48*64 + 48
            int kk = 3072 + lane;
            f4 v = x4[kk];
            a0 = fma4(ntload(W0 + kk), v, a0);
            a1 = fma4(ntload(W1 + kk), v, a1);
            a2 = fma4(ntload(W2 + kk), v, a2);
            a3 = fma4(ntload(W3 + kk), v, a3);
        }
        a0 = wave_reduce(a0);
        a1 = wave_reduce(a1);
        a2 = wave_reduce(a2);
        a3 = wave_reduce(a3);
        if (lane == 0) {
            ws[GI_OFF + r]     = a0 + b_ih[r];
            ws[GI_OFF + r + 1] = a1 + b_ih[r + 1];
            ws[GI_OFF + r + 2] = a2 + b_ih[r + 2];
            ws[GI_OFF + r + 3] = a3 + b_ih[r + 3];
        }
    } else {
        // 12 rows per wave in 3 passes of 4; h0 (16 KB) L2-resident
        int base = (b - GI_NB) * GH_RPB + wave * GH_RPW;
        const f4* h4 = (const f4*)h0;
        #pragma unroll
        for (int p = 0; p < GH_RPW; p += 4) {
            int r = base + p;
            const f4* W0 = (const f4*)W_hh + (size_t)r * H4;
            const f4* W1 = W0 + H4;
            const f4* W2 = W1 + H4;
            const f4* W3 = W2 + H4;
            float a0 = 0.f, a1 = 0.f, a2 = 0.f, a3 = 0.f;
            int k = lane;
            #pragma unroll 4
            for (int i = 0; i < 16; ++i, k += 64) {   // 1024 = 16*64 exactly
                f4 v = h4[k];
                a0 = fma4(ntload(W0 + k), v, a0);
                a1 = fma4(ntload(W1 + k), v, a1);
                a2 = fma4(ntload(W2 + k), v, a2);
                a3 = fma4(ntload(W3 + k), v, a3);
            }
            a0 = wave_reduce(a0);
            a1 = wave_reduce(a1);
            a2 = wave_reduce(a2);
            a3 = wave_reduce(a3);
            if (lane == 0) {
                ws[GH_OFF + r]     = a0 + b_hh[r];
                ws[GH_OFF + r + 1] = a1 + b_hh[r + 1];
                ws[GH_OFF + r + 2] = a2 + b_hh[r + 2];
                ws[GH_OFF + r + 3] = a3 + b_hh[r + 3];
            }
        }
    }

    // -------- last block runs the GRU combine (counter only touched post-work) -----
    __threadfence();                           // release gi/gh (L2 writeback)
    if (tid == 0) {
        int old = __hip_atomic_fetch_add((int*)(ws + SYNC_OFF), 1,
                                         __ATOMIC_ACQ_REL,
                                         __HIP_MEMORY_SCOPE_AGENT);
        sLast = (old == NBLK - 1);
    }
    __syncthreads();
    if (sLast) {
        __threadfence();                       // acquire gi/gh (invalidate stale)
        #pragma unroll
        for (int t = 0; t < 16; ++t) {
            int j = t * 256 + tid;             // 4096 = 16*256, coalesced
            float ir  = ws[GI_OFF + j];
            float iz  = ws[GI_OFF + HSZ + j];
            float in_ = ws[GI_OFF + 2 * HSZ + j];
            float hr  = ws[GH_OFF + j];
            float hz  = ws[GH_OFF + HSZ + j];
            float hn  = ws[GH_OFF + 2 * HSZ + j];
            float r = 1.f / (1.f + __expf(-(ir + hr)));
            float z = 1.f / (1.f + __expf(-(iz + hz)));
            float n = tanhf(in_ + r * hn);
            float h = (1.f - z) * n + z * h0[j];
            out[j]       = h;
            out[HSZ + j] = h;
        }
    }
}

extern "C" void kernel_launch(void* const* d_in, const int* in_sizes, int n_in,
                              void* d_out, int out_size, void* d_ws, size_t ws_size,
                              hipStream_t stream) {
    const float* data    = (const float*)d_in[0];
    const float* hidden  = (const float*)d_in[1];
    const float* fgat_W  = (const float*)d_in[2];
    const float* fgat_al = (const float*)d_in[3];
    // d_in[4] = fgat_ar (unused: er[0] = h[0]*ar = 0 since padded row 0 is zero)
    const float* fgat_b  = (const float*)d_in[5];
    const float* tgat_W  = (const float*)d_in[6];
    const float* tgat_al = (const float*)d_in[7];
    // d_in[8] = tgat_ar (unused, same reason)
    const float* tgat_b  = (const float*)d_in[9];
    const float* W_ih    = (const float*)d_in[10];
    const float* W_hh    = (const float*)d_in[11];
    const float* b_ih    = (const float*)d_in[12];
    const float* b_hh    = (const float*)d_in[13];
    float* ws  = (float*)d_ws;
    float* out = (float*)d_out;

    // zero the completion counter (ws poisoned once, never re-poisoned)
    hipMemsetAsync((char*)d_ws + SYNC_OFF * sizeof(float), 0, sizeof(int), stream);
    gat8<<<8, 256, 0, stream>>>(data, fgat_W, fgat_al, fgat_b,
                                tgat_W, tgat_al, tgat_b, ws);
    big_matvec<<<NBLK, 256, 0, stream>>>(W_ih, W_hh, hidden, b_ih, b_hh, ws, out);
}

// Round 8
// 132.610 us; speedup vs baseline: 2.7783x; 2.7783x over previous
//
#include <hip/hip_runtime.h>

#define FEATS 64
#define HSZ   4096
#define ISZ   12480          // (FEATS+1)*FEATS*3
#define I4    (ISZ/4)        // 3120 float4
#define H4    (HSZ/4)        // 1024 float4

// workspace layout (float offsets)
#define X_OFF  0             // 12480
#define GI_OFF 12480         // 12288
#define GH_OFF 24768         // 12288

#define GI_RPW 4                      // rows per wave (GI)
#define GI_RPB 16                     // rows per block
#define GH_RPW 12                     // rows per wave (GH), 3 passes of 4
#define GH_RPB 48
#define GI_NB  (3 * HSZ / GI_RPB)     // 768
#define GH_NB  (3 * HSZ / GH_RPB)     // 256  -> 1024 blocks = 4/CU, one pass

typedef float f4 __attribute__((ext_vector_type(4)));

// ---------------- A: GAT, 8 blocks = {feat,time} x 4 head-quarters ------------------
// Softmax is per-head (column), so splitting by heads has no cross-block deps.
__global__ __launch_bounds__(256)
void gat8(const float* __restrict__ data,
          const float* __restrict__ fW, const float* __restrict__ fal,
          const float* __restrict__ fb,
          const float* __restrict__ tW, const float* __restrict__ tal,
          const float* __restrict__ tb,
          float* __restrict__ ws) {
    __shared__ float ld[64][65];   // data (w=0) or data^T (w=1)
    __shared__ float Wl[64][17];   // 16-head slice of W
    __shared__ float hb[64][17];   // h slice
    __shared__ float out0[16];
    int b = blockIdx.x;
    int w = b >> 2, q = b & 3;     // w: which GAT; q: head quarter
    int tid = threadIdx.x;
    const float* Wg = w ? tW  : fW;
    const float* al = w ? tal : fal;
    const float* bb = w ? tb  : fb;

    for (int i = tid; i < 4096; i += 256) {
        int r = i >> 6, c = i & 63;
        float v = data[i];
        if (w) ld[c][r] = v; else ld[r][c] = v;
    }
    for (int i = tid; i < 1024; i += 256) {
        int k = i >> 4, jj = i & 15;
        Wl[k][jj] = Wg[k * 64 + q * 16 + jj];
    }
    __syncthreads();

    // h[v][jj] = sum_k ld[v][k] * Wl[k][jj]; wave jr owns heads jr*4..jr*4+3
    {
        int v = tid & 63, jr = tid >> 6;
        float a0 = 0.f, a1 = 0.f, a2 = 0.f, a3 = 0.f;
        #pragma unroll 8
        for (int k = 0; k < 64; ++k) {
            float dv = ld[v][k];
            a0 = fmaf(dv, Wl[k][jr * 4 + 0], a0);
            a1 = fmaf(dv, Wl[k][jr * 4 + 1], a1);
            a2 = fmaf(dv, Wl[k][jr * 4 + 2], a2);
            a3 = fmaf(dv, Wl[k][jr * 4 + 3], a3);
        }
        hb[v][jr * 4 + 0] = a0;
        hb[v][jr * 4 + 1] = a1;
        hb[v][jr * 4 + 2] = a2;
        hb[v][jr * 4 + 3] = a3;
    }
    __syncthreads();

    // star softmax per head; node 0 has h=0 -> e=0 (ar drops out entirely)
    if (tid < 16) {
        int jj = tid;
        float a = al[q * 16 + jj];
        float m = 0.f;                     // includes node-0 term e=0
        for (int v = 0; v < 64; ++v) {
            float e = hb[v][jj] * a;
            e = e > 0.f ? e : 0.2f * e;
            m = fmaxf(m, e);
        }
        float sum = __expf(0.f - m);       // node-0 term (zero numerator)
        float num = 0.f;
        for (int v = 0; v < 64; ++v) {
            float hv = hb[v][jj];
            float e  = hv * a;
            e = e > 0.f ? e : 0.2f * e;
            float p  = __expf(e - m);
            sum += p;
            num += p * hv;
        }
        out0[jj] = num / sum;
    }
    __syncthreads();

    // x[(n*64+f)*3 + c] for this block's 16 heads: c = 1+w; block w=0 also c0
    for (int i = tid; i < 1040; i += 256) {     // 65 nodes x 16 heads
        int n = i >> 4, ff = i & 15;
        int f = q * 16 + ff;
        float val = ((n == 0) ? out0[ff] : hb[n - 1][ff]) + bb[f];
        ws[X_OFF + (n * 64 + f) * 3 + 1 + w] = val;
        if (w == 0)
            ws[X_OFF + (n * 64 + f) * 3] = (n == 0) ? 0.f : ld[n - 1][f];
    }
}

// ---------------- B: the two big matvecs (memory-bound; 815 MB of weights) ---------
__device__ __forceinline__ float wave_reduce(float v) {
    #pragma unroll
    for (int off = 32; off > 0; off >>= 1) v += __shfl_down(v, off);
    return v;
}

__device__ __forceinline__ float fma4(f4 w, f4 v, float a) {
    return fmaf(w.x, v.x, fmaf(w.y, v.y, fmaf(w.z, v.z, fmaf(w.w, v.w, a))));
}

__device__ __forceinline__ f4 ntload(const f4* p) {
    return __builtin_nontemporal_load(p);   // use-once weights: bypass L2 insert
}

__global__ __launch_bounds__(256, 4)
void big_matvec(const float* __restrict__ W_ih,
                const float* __restrict__ W_hh,
                const float* __restrict__ h0,
                float* __restrict__ ws) {
    int b    = blockIdx.x;
    int wave = threadIdx.x >> 6;
    int lane = threadIdx.x & 63;

    if (b < GI_NB) {
        // 4 rows per wave, 49.9 KB each; x re-read once per 4 rows (L2-resident)
        int r = b * GI_RPB + wave * GI_RPW;
        const f4* x4 = (const f4*)(ws + X_OFF);
        const f4* W0 = (const f4*)W_ih + (size_t)r * I4;
        const f4* W1 = W0 + I4;
        const f4* W2 = W1 + I4;
        const f4* W3 = W2 + I4;
        float a0 = 0.f, a1 = 0.f, a2 = 0.f, a3 = 0.f;
        int k = lane;
        #pragma unroll 4
        for (int i = 0; i < 48; ++i, k += 64) {
            f4 v = x4[k];
            a0 = fma4(ntload(W0 + k), v, a0);
            a1 = fma4(ntload(W1 + k), v, a1);
            a2 = fma4(ntload(W2 + k), v, a2);
            a3 = fma4(ntload(W3 + k), v, a3);
        }
        if (lane < 48) {                       // remainder: 3120 = 48*64 + 48
            int kk = 3072 + lane;
            f4 v = x4[kk];
            a0 = fma4(ntload(W0 + kk), v, a0);
            a1 = fma4(ntload(W1 + kk), v, a1);
            a2 = fma4(ntload(W2 + kk), v, a2);
            a3 = fma4(ntload(W3 + kk), v, a3);
        }
        a0 = wave_reduce(a0);
        a1 = wave_reduce(a1);
        a2 = wave_reduce(a2);
        a3 = wave_reduce(a3);
        if (lane == 0) {
            ws[GI_OFF + r]     = a0;
            ws[GI_OFF + r + 1] = a1;
            ws[GI_OFF + r + 2] = a2;
            ws[GI_OFF + r + 3] = a3;
        }
    } else {
        // 12 rows per wave in 3 passes of 4; h0 (16 KB) L2-resident
        int base = (b - GI_NB) * GH_RPB + wave * GH_RPW;
        const f4* h4 = (const f4*)h0;
        #pragma unroll
        for (int p = 0; p < GH_RPW; p += 4) {
            int r = base + p;
            const f4* W0 = (const f4*)W_hh + (size_t)r * H4;
            const f4* W1 = W0 + H4;
            const f4* W2 = W1 + H4;
            const f4* W3 = W2 + H4;
            float a0 = 0.f, a1 = 0.f, a2 = 0.f, a3 = 0.f;
            int k = lane;
            #pragma unroll 4
            for (int i = 0; i < 16; ++i, k += 64) {   // 1024 = 16*64 exactly
                f4 v = h4[k];
                a0 = fma4(ntload(W0 + k), v, a0);
                a1 = fma4(ntload(W1 + k), v, a1);
                a2 = fma4(ntload(W2 + k), v, a2);
                a3 = fma4(ntload(W3 + k), v, a3);
            }
            a0 = wave_reduce(a0);
            a1 = wave_reduce(a1);
            a2 = wave_reduce(a2);
            a3 = wave_reduce(a3);
            if (lane == 0) {
                ws[GH_OFF + r]     = a0;
                ws[GH_OFF + r + 1] = a1;
                ws[GH_OFF + r + 2] = a2;
                ws[GH_OFF + r + 3] = a3;
            }
        }
    }
}

// ---------------- C: GRU gate math + write both output copies ----------------------
__global__ void gru_combine(const float* __restrict__ h0,
                            const float* __restrict__ b_ih,
                            const float* __restrict__ b_hh,
                            const float* __restrict__ ws,
                            float* __restrict__ out) {
    int j = blockIdx.x * 256 + threadIdx.x;
    if (j >= HSZ) return;
    const float* gi = ws + GI_OFF;
    const float* gh = ws + GH_OFF;
    float ir  = gi[j]         + b_ih[j];
    float iz  = gi[HSZ + j]   + b_ih[HSZ + j];
    float in_ = gi[2*HSZ + j] + b_ih[2*HSZ + j];
    float hr  = gh[j]         + b_hh[j];
    float hz  = gh[HSZ + j]   + b_hh[HSZ + j];
    float hn  = gh[2*HSZ + j] + b_hh[2*HSZ + j];
    float r = 1.f / (1.f + expf(-(ir + hr)));
    float z = 1.f / (1.f + expf(-(iz + hz)));
    float n = tanhf(in_ + r * hn);
    float h = (1.f - z) * n + z * h0[j];
    out[j]       = h;
    out[HSZ + j] = h;
}

extern "C" void kernel_launch(void* const* d_in, const int* in_sizes, int n_in,
                              void* d_out, int out_size, void* d_ws, size_t ws_size,
                              hipStream_t stream) {
    const float* data    = (const float*)d_in[0];
    const float* hidden  = (const float*)d_in[1];
    const float* fgat_W  = (const float*)d_in[2];
    const float* fgat_al = (const float*)d_in[3];
    // d_in[4] = fgat_ar (unused: er[0] = h[0]*ar = 0 since padded row 0 is zero)
    const float* fgat_b  = (const float*)d_in[5];
    const float* tgat_W  = (const float*)d_in[6];
    const float* tgat_al = (const float*)d_in[7];
    // d_in[8] = tgat_ar (unused, same reason)
    const float* tgat_b  = (const float*)d_in[9];
    const float* W_ih    = (const float*)d_in[10];
    const float* W_hh    = (const float*)d_in[11];
    const float* b_ih    = (const float*)d_in[12];
    const float* b_hh    = (const float*)d_in[13];
    float* ws  = (float*)d_ws;
    float* out = (float*)d_out;

    gat8<<<8, 256, 0, stream>>>(data, fgat_W, fgat_al, fgat_b,
                                tgat_W, tgat_al, tgat_b, ws);
    big_matvec<<<GI_NB + GH_NB, 256, 0, stream>>>(W_ih, W_hh, hidden, ws);
    gru_combine<<<HSZ / 256, 256, 0, stream>>>(hidden, b_ih, b_hh, ws, out);
}